// Round 3
// baseline (621.570 us; speedup 1.0000x reference)
//
#include <hip/hip_runtime.h>

#define N_NODES 100000
#define DIM 128
#define NBINS 782   // ceil(100000 / 128)
#define BINCAP 2560 // bin edges ~ Poisson(2048), sigma~45; 2560 = +11 sigma
#define CAP 64      // per-node in-degree cap; P(Poisson16 > 64) ~ 1e-14

typedef __attribute__((ext_vector_type(8))) short bf16x8;
typedef __attribute__((ext_vector_type(4))) float f32x4;

__device__ __forceinline__ unsigned short f2bf(float f) {
  unsigned u = __builtin_bit_cast(unsigned, f);
  u += 0x7fff + ((u >> 16) & 1);  // RNE
  return (unsigned short)(u >> 16);
}
__device__ __forceinline__ float bf2f(unsigned short h) {
  unsigned u = ((unsigned)h) << 16;
  return __builtin_bit_cast(float, u);
}

// ---------------------------------------------------------------------------
// Kernel 1: dual GEMM via bf16 MFMA.  self = x@W1^T (fp32 -> out),
// neigh = x@W2^T (bf16 -> ws).  Block: 256 thr / 4 waves, tile 128 nodes x
// 256 j, K=128 in one LDS stage.  Wave w owns j in [64w, 64w+64): waves 0-1
// -> self, 2-3 -> neigh.  B frags register-resident (64 VGPR), A staged
// fp32->bf16 in LDS rows padded to 136 (272B: 2-way bank alias only).
// ---------------------------------------------------------------------------
__global__ __launch_bounds__(256, 2) void gemm_kernel(
    const float* __restrict__ x, const float* __restrict__ W1,
    const float* __restrict__ W2, float* __restrict__ self_out,
    unsigned short* __restrict__ neigh) {
  __shared__ unsigned short xs[128 * 136];  // 34 KB

  const int tid = threadIdx.x;
  const int lane = tid & 63;
  const int w = tid >> 6;
  const int nb = blockIdx.x * 128;
  const int quad = lane >> 4;
  const int l15 = lane & 15;

  // B fragments: B[k][n] = W[j=n][k];  j = 64w + 16nt + l15, k = 32ks + 8quad + t
  bf16x8 bfrag[4][4];
#pragma unroll
  for (int nt = 0; nt < 4; ++nt) {
    const int j = w * 64 + nt * 16 + l15;
    const float* Wrow =
        (j < 128) ? (W1 + (size_t)j * DIM) : (W2 + (size_t)(j - 128) * DIM);
#pragma unroll
    for (int ks = 0; ks < 4; ++ks) {
      const float* p = Wrow + ks * 32 + quad * 8;
      const float4 lo = *(const float4*)(p);
      const float4 hi = *(const float4*)(p + 4);
      bf16x8 t;
      t[0] = (short)f2bf(lo.x); t[1] = (short)f2bf(lo.y);
      t[2] = (short)f2bf(lo.z); t[3] = (short)f2bf(lo.w);
      t[4] = (short)f2bf(hi.x); t[5] = (short)f2bf(hi.y);
      t[6] = (short)f2bf(hi.z); t[7] = (short)f2bf(hi.w);
      bfrag[nt][ks] = t;
    }
  }

  // stage A: 128 rows x 128 k, fp32 -> bf16, row stride 136
#pragma unroll
  for (int it = 0; it < 16; ++it) {
    const int v = tid + it * 256;
    const int m = v >> 5, q = v & 31;
    float4 val = make_float4(0.f, 0.f, 0.f, 0.f);
    if (nb + m < N_NODES)
      val = *(const float4*)(x + (size_t)(nb + m) * DIM + 4 * q);
    unsigned short* d = &xs[m * 136 + 4 * q];
    d[0] = f2bf(val.x); d[1] = f2bf(val.y);
    d[2] = f2bf(val.z); d[3] = f2bf(val.w);
  }
  __syncthreads();

  f32x4 acc[8][4];
#pragma unroll
  for (int mt = 0; mt < 8; ++mt)
#pragma unroll
    for (int nt = 0; nt < 4; ++nt) acc[mt][nt] = (f32x4){0.f, 0.f, 0.f, 0.f};

  // A frag: A[m = 16mt + l15][k = 32ks + 8quad + t]
#pragma unroll
  for (int ks = 0; ks < 4; ++ks) {
#pragma unroll
    for (int mt = 0; mt < 8; ++mt) {
      const bf16x8 afrag =
          *(const bf16x8*)&xs[(mt * 16 + l15) * 136 + ks * 32 + quad * 8];
#pragma unroll
      for (int nt = 0; nt < 4; ++nt)
        acc[mt][nt] = __builtin_amdgcn_mfma_f32_16x16x32_bf16(
            afrag, bfrag[nt][ks], acc[mt][nt], 0, 0, 0);
    }
  }

  // epilogue: D[row = 16mt + 4quad + r][col = 64w + 16nt + l15]
#pragma unroll
  for (int mt = 0; mt < 8; ++mt) {
#pragma unroll
    for (int nt = 0; nt < 4; ++nt) {
      const int j = w * 64 + nt * 16 + l15;
#pragma unroll
      for (int r = 0; r < 4; ++r) {
        const int node = nb + mt * 16 + quad * 4 + r;
        if (node < N_NODES) {
          if (w < 2)
            self_out[(size_t)node * DIM + j] = acc[mt][nt][r];
          else
            neigh[(size_t)node * DIM + (j - 128)] = f2bf(acc[mt][nt][r]);
        }
      }
    }
  }
}

// ---------------------------------------------------------------------------
// Kernel 2: coarse binning by row>>7.  ~800 streaming write heads -> lines
// fill in L2, write traffic ~ 13 MB instead of 96 MB.
// ---------------------------------------------------------------------------
__global__ __launch_bounds__(256) void bin_kernel(
    const int* __restrict__ rows, const int* __restrict__ cols,
    int* __restrict__ cursors, int2* __restrict__ binned,
    const unsigned short* __restrict__ neigh, float* __restrict__ out,
    int n_edges) {
  const int e = blockIdx.x * 256 + threadIdx.x;
  if (e >= n_edges) return;
  const int r = rows[e];
  const int c = cols[e];
  const int b = r >> 7;
  const int pos = atomicAdd(&cursors[b], 1);
  if (pos < BINCAP) {
    binned[(size_t)b * BINCAP + pos] = make_int2(r, c);
  } else {
    // essentially-never overflow: add contribution directly (pre-ReLU)
    for (int d = 0; d < DIM; ++d)
      atomicAdd(&out[(size_t)r * DIM + d], bf2f(neigh[(size_t)c * DIM + d]));
  }
}

// ---------------------------------------------------------------------------
// Kernel 3: per-bin LDS counting-sort + per-node gather-reduce (bf16) +
// fused add-self + ReLU.  One block per bin (128 nodes), one wave per node.
// ---------------------------------------------------------------------------
__global__ __launch_bounds__(256) void agg_kernel(
    const int* __restrict__ cursors, const int2* __restrict__ binned,
    const unsigned short* __restrict__ neigh, float* __restrict__ out) {
  __shared__ int cnt[128];
  __shared__ int lists[128][CAP];  // 32 KB

  const int tid = threadIdx.x;
  const int b = blockIdx.x;
  const int base = b << 7;

  if (tid < 128) cnt[tid] = 0;
  __syncthreads();

  int nb = cursors[b];
  if (nb > BINCAP) nb = BINCAP;
  for (int i = tid; i < nb; i += 256) {
    const int2 e = binned[(size_t)b * BINCAP + i];
    const int rl = e.x & 127;
    const int slot = atomicAdd(&cnt[rl], 1);
    if (slot < CAP) {
      lists[rl][slot] = e.y;
    } else {
      // essentially-never overflow: direct add (completes before barrier)
      for (int d = 0; d < DIM; ++d)
        atomicAdd(&out[(size_t)e.x * DIM + d],
                  bf2f(neigh[(size_t)e.y * DIM + d]));
    }
  }
  __syncthreads();

  const int w = tid >> 6, l = tid & 63;
  const unsigned* ng = (const unsigned*)neigh;  // bf16x2 per dword
  for (int rl = w; rl < 128; rl += 4) {
    const int node = base + rl;
    if (node >= N_NODES) break;
    int deg = cnt[rl];
    if (deg > CAP) deg = CAP;

    float ax = 0.f, ay = 0.f;
    int d = 0;
    for (; d + 4 <= deg; d += 4) {
      const int4 c4 = *(const int4*)&lists[rl][d];
      const unsigned u0 = ng[(size_t)c4.x * 64 + l];
      const unsigned u1 = ng[(size_t)c4.y * 64 + l];
      const unsigned u2 = ng[(size_t)c4.z * 64 + l];
      const unsigned u3 = ng[(size_t)c4.w * 64 + l];
      ax += (__builtin_bit_cast(float, u0 << 16) +
             __builtin_bit_cast(float, u1 << 16)) +
            (__builtin_bit_cast(float, u2 << 16) +
             __builtin_bit_cast(float, u3 << 16));
      ay += (__builtin_bit_cast(float, u0 & 0xffff0000u) +
             __builtin_bit_cast(float, u1 & 0xffff0000u)) +
            (__builtin_bit_cast(float, u2 & 0xffff0000u) +
             __builtin_bit_cast(float, u3 & 0xffff0000u));
    }
    for (; d < deg; ++d) {
      const unsigned u = ng[(size_t)lists[rl][d] * 64 + l];
      ax += __builtin_bit_cast(float, u << 16);
      ay += __builtin_bit_cast(float, u & 0xffff0000u);
    }

    float2 s = *(const float2*)(out + (size_t)node * DIM + 2 * l);
    s.x = fmaxf(s.x + ax, 0.f);
    s.y = fmaxf(s.y + ay, 0.f);
    *(float2*)(out + (size_t)node * DIM + 2 * l) = s;
  }
}

extern "C" void kernel_launch(void* const* d_in, const int* in_sizes, int n_in,
                              void* d_out, int out_size, void* d_ws,
                              size_t ws_size, hipStream_t stream) {
  const float* x = (const float*)d_in[0];
  const int* edge_index = (const int*)d_in[1];  // (2,E): [0]=row(dst), [1]=col(src)
  const float* W1 = (const float*)d_in[2];
  const float* W2 = (const float*)d_in[3];
  float* out = (float*)d_out;

  const int n_edges = in_sizes[1] / 2;
  const int* rows = edge_index;
  const int* cols = edge_index + n_edges;

  // ws layout: neigh bf16 (25.6 MB) | binned int2 (16.0 MB) | cursors (3 KB)
  unsigned short* neigh = (unsigned short*)d_ws;
  int2* binned = (int2*)((char*)d_ws + (size_t)N_NODES * DIM * 2);
  int* cursors =
      (int*)((char*)binned + (size_t)NBINS * BINCAP * sizeof(int2));

  hipMemsetAsync(cursors, 0, NBINS * sizeof(int), stream);

  const int n_tiles = (N_NODES + 127) / 128;  // 782
  gemm_kernel<<<n_tiles, 256, 0, stream>>>(x, W1, W2, out, neigh);
  bin_kernel<<<(n_edges + 255) / 256, 256, 0, stream>>>(
      rows, cols, cursors, binned, neigh, out, n_edges);
  agg_kernel<<<NBINS, 256, 0, stream>>>(cursors, binned, neigh, out);
}

// Round 4
// 351.064 us; speedup vs baseline: 1.7705x; 1.7705x over previous
//
#include <hip/hip_runtime.h>

#define N_NODES 100000
#define DIM 128
#define CAP 64  // per-node in-degree cap; max observed deg for Poisson(16) over 100k ~ low 40s

typedef __attribute__((ext_vector_type(8))) short bf16x8;
typedef __attribute__((ext_vector_type(4))) float f32x4;

__device__ __forceinline__ unsigned short f2bf(float f) {
  unsigned u = __builtin_bit_cast(unsigned, f);
  u += 0x7fff + ((u >> 16) & 1);  // RNE
  return (unsigned short)(u >> 16);
}
__device__ __forceinline__ float bf2f(unsigned short h) {
  unsigned u = ((unsigned)h) << 16;
  return __builtin_bit_cast(float, u);
}

// ---------------------------------------------------------------------------
// Kernel 1: dual GEMM via bf16 MFMA.  self = x@W1^T (fp32 -> out),
// neigh = x@W2^T (bf16 -> ws).  Block: 256 thr / 4 waves, tile 128 nodes x
// 256 j, K=128 in one LDS stage.  Wave w owns j in [64w, 64w+64): waves 0-1
// -> self, 2-3 -> neigh.  B frags register-resident, A staged fp32->bf16 in
// LDS rows padded to 136 shorts (272B -> only 2-way bank alias, free).
// ---------------------------------------------------------------------------
__global__ __launch_bounds__(256, 2) void gemm_kernel(
    const float* __restrict__ x, const float* __restrict__ W1,
    const float* __restrict__ W2, float* __restrict__ self_out,
    unsigned short* __restrict__ neigh) {
  __shared__ unsigned short xs[128 * 136];  // 34 KB

  const int tid = threadIdx.x;
  const int lane = tid & 63;
  const int w = tid >> 6;
  const int nb = blockIdx.x * 128;
  const int quad = lane >> 4;
  const int l15 = lane & 15;

  // B fragments: B[k][n] = W[j=n][k];  j = 64w + 16nt + l15, k = 32ks + 8quad + t
  bf16x8 bfrag[4][4];
#pragma unroll
  for (int nt = 0; nt < 4; ++nt) {
    const int j = w * 64 + nt * 16 + l15;
    const float* Wrow =
        (j < 128) ? (W1 + (size_t)j * DIM) : (W2 + (size_t)(j - 128) * DIM);
#pragma unroll
    for (int ks = 0; ks < 4; ++ks) {
      const float* p = Wrow + ks * 32 + quad * 8;
      const float4 lo = *(const float4*)(p);
      const float4 hi = *(const float4*)(p + 4);
      bf16x8 t;
      t[0] = (short)f2bf(lo.x); t[1] = (short)f2bf(lo.y);
      t[2] = (short)f2bf(lo.z); t[3] = (short)f2bf(lo.w);
      t[4] = (short)f2bf(hi.x); t[5] = (short)f2bf(hi.y);
      t[6] = (short)f2bf(hi.z); t[7] = (short)f2bf(hi.w);
      bfrag[nt][ks] = t;
    }
  }

  // stage A: 128 rows x 128 k, fp32 -> bf16, row stride 136
#pragma unroll
  for (int it = 0; it < 16; ++it) {
    const int v = tid + it * 256;
    const int m = v >> 5, q = v & 31;
    float4 val = make_float4(0.f, 0.f, 0.f, 0.f);
    if (nb + m < N_NODES)
      val = *(const float4*)(x + (size_t)(nb + m) * DIM + 4 * q);
    unsigned short* d = &xs[m * 136 + 4 * q];
    d[0] = f2bf(val.x); d[1] = f2bf(val.y);
    d[2] = f2bf(val.z); d[3] = f2bf(val.w);
  }
  __syncthreads();

  f32x4 acc[8][4];
#pragma unroll
  for (int mt = 0; mt < 8; ++mt)
#pragma unroll
    for (int nt = 0; nt < 4; ++nt) acc[mt][nt] = (f32x4){0.f, 0.f, 0.f, 0.f};

  // A frag: A[m = 16mt + l15][k = 32ks + 8quad + t]
#pragma unroll
  for (int ks = 0; ks < 4; ++ks) {
#pragma unroll
    for (int mt = 0; mt < 8; ++mt) {
      const bf16x8 afrag =
          *(const bf16x8*)&xs[(mt * 16 + l15) * 136 + ks * 32 + quad * 8];
#pragma unroll
      for (int nt = 0; nt < 4; ++nt)
        acc[mt][nt] = __builtin_amdgcn_mfma_f32_16x16x32_bf16(
            afrag, bfrag[nt][ks], acc[mt][nt], 0, 0, 0);
    }
  }

  // epilogue: D[row = 16mt + 4quad + r][col = 64w + 16nt + l15]
#pragma unroll
  for (int mt = 0; mt < 8; ++mt) {
#pragma unroll
    for (int nt = 0; nt < 4; ++nt) {
      const int j = w * 64 + nt * 16 + l15;
#pragma unroll
      for (int r = 0; r < 4; ++r) {
        const int node = nb + mt * 16 + quad * 4 + r;
        if (node < N_NODES) {
          if (w < 2)
            self_out[(size_t)node * DIM + j] = acc[mt][nt][r];
          else
            neigh[(size_t)node * DIM + (j - 128)] = f2bf(acc[mt][nt][r]);
        }
      }
    }
  }
}

// ---------------------------------------------------------------------------
// Kernel 2: padded-CSR fill, TRANSPOSED layout bucket_T[slot][node].
// 100k cursors -> ~16 edges/counter, no atomic contention (R3 lesson).
// Writes to slot-plane s are dense over a 400KB region -> line merging,
// written-byte footprint exactly 6.4 MB (vs 96 MB writeback in R2 layout).
// ---------------------------------------------------------------------------
__global__ __launch_bounds__(256) void fill_kernel(
    const int* __restrict__ rows, const int* __restrict__ cols,
    int* __restrict__ counts, int* __restrict__ bucket_t,
    const unsigned short* __restrict__ neigh, float* __restrict__ out,
    int n_edges) {
  const int e = blockIdx.x * 256 + threadIdx.x;
  if (e >= n_edges) return;
  const int r = rows[e];
  const int c = cols[e];
  const int slot = atomicAdd(&counts[r], 1);
  if (slot < CAP) {
    bucket_t[(size_t)slot * N_NODES + r] = c;
  } else {
    // essentially-never overflow: add contribution directly (pre-ReLU; self
    // part of out is already written by gemm_kernel, agg clamps deg to CAP)
    for (int d = 0; d < DIM; ++d)
      atomicAdd(&out[(size_t)r * DIM + d], bf2f(neigh[(size_t)c * DIM + d]));
  }
}

// ---------------------------------------------------------------------------
// Kernel 3: per-node gather-reduce (bf16) + fused add-self + ReLU.
// One wave per node, lane l owns dword l (2 bf16). Index loads are
// wave-uniform; 4-deep ILP on the gathers. No atomics.
// ---------------------------------------------------------------------------
__global__ __launch_bounds__(256) void agg_kernel(
    const int* __restrict__ counts, const int* __restrict__ bucket_t,
    const unsigned short* __restrict__ neigh, float* __restrict__ out) {
  const int node = blockIdx.x * 4 + (threadIdx.x >> 6);
  if (node >= N_NODES) return;
  const int l = threadIdx.x & 63;
  int deg = counts[node];
  if (deg > CAP) deg = CAP;

  const unsigned* ng = (const unsigned*)neigh;  // bf16x2 per dword
  float ax = 0.f, ay = 0.f;
  int d = 0;
  for (; d + 4 <= deg; d += 4) {
    const int c0 = bucket_t[(size_t)(d + 0) * N_NODES + node];
    const int c1 = bucket_t[(size_t)(d + 1) * N_NODES + node];
    const int c2 = bucket_t[(size_t)(d + 2) * N_NODES + node];
    const int c3 = bucket_t[(size_t)(d + 3) * N_NODES + node];
    const unsigned u0 = ng[(size_t)c0 * 64 + l];
    const unsigned u1 = ng[(size_t)c1 * 64 + l];
    const unsigned u2 = ng[(size_t)c2 * 64 + l];
    const unsigned u3 = ng[(size_t)c3 * 64 + l];
    ax += (__builtin_bit_cast(float, u0 << 16) +
           __builtin_bit_cast(float, u1 << 16)) +
          (__builtin_bit_cast(float, u2 << 16) +
           __builtin_bit_cast(float, u3 << 16));
    ay += (__builtin_bit_cast(float, u0 & 0xffff0000u) +
           __builtin_bit_cast(float, u1 & 0xffff0000u)) +
          (__builtin_bit_cast(float, u2 & 0xffff0000u) +
           __builtin_bit_cast(float, u3 & 0xffff0000u));
  }
  for (; d < deg; ++d) {
    const int c = bucket_t[(size_t)d * N_NODES + node];
    const unsigned u = ng[(size_t)c * 64 + l];
    ax += __builtin_bit_cast(float, u << 16);
    ay += __builtin_bit_cast(float, u & 0xffff0000u);
  }

  float2 s = *(const float2*)(out + (size_t)node * DIM + 2 * l);
  s.x = fmaxf(s.x + ax, 0.f);
  s.y = fmaxf(s.y + ay, 0.f);
  *(float2*)(out + (size_t)node * DIM + 2 * l) = s;
}

extern "C" void kernel_launch(void* const* d_in, const int* in_sizes, int n_in,
                              void* d_out, int out_size, void* d_ws,
                              size_t ws_size, hipStream_t stream) {
  const float* x = (const float*)d_in[0];
  const int* edge_index = (const int*)d_in[1];  // (2,E): [0]=row(dst), [1]=col(src)
  const float* W1 = (const float*)d_in[2];
  const float* W2 = (const float*)d_in[3];
  float* out = (float*)d_out;

  const int n_edges = in_sizes[1] / 2;
  const int* rows = edge_index;
  const int* cols = edge_index + n_edges;

  // ws layout: neigh bf16 (25.6 MB) | counts (400 KB) | bucket_T (25.6 MB)
  unsigned short* neigh = (unsigned short*)d_ws;
  int* counts = (int*)((char*)d_ws + (size_t)N_NODES * DIM * 2);
  int* bucket_t = counts + N_NODES;

  hipMemsetAsync(counts, 0, N_NODES * sizeof(int), stream);

  const int n_tiles = (N_NODES + 127) / 128;  // 782
  gemm_kernel<<<n_tiles, 256, 0, stream>>>(x, W1, W2, out, neigh);
  fill_kernel<<<(n_edges + 255) / 256, 256, 0, stream>>>(
      rows, cols, counts, bucket_t, neigh, out, n_edges);
  agg_kernel<<<(N_NODES + 3) / 4, 256, 0, stream>>>(counts, bucket_t, neigh,
                                                    out);
}

// Round 5
// 293.246 us; speedup vs baseline: 2.1196x; 1.1972x over previous
//
#include <hip/hip_runtime.h>

#define N_NODES 100000
#define DIM 128
#define NB 196       // node bins of 512: bin = r >> 9
#define NFILL 256    // fill blocks; chunk = E/256 = 6250
#define FCAP 80      // per-(block,bin) slots; mean 32, P(Poisson>80)~1e-11
#define ENTCAP 8704  // per-bin CSR capacity; mean 8163, ~6 sigma

typedef __attribute__((ext_vector_type(8))) short bf16x8;
typedef __attribute__((ext_vector_type(4))) float f32x4;

__device__ __forceinline__ unsigned short f2bf(float f) {
  unsigned u = __builtin_bit_cast(unsigned, f);
  u += 0x7fff + ((u >> 16) & 1);  // RNE
  return (unsigned short)(u >> 16);
}
__device__ __forceinline__ float bf2f(unsigned short h) {
  unsigned u = ((unsigned)h) << 16;
  return __builtin_bit_cast(float, u);
}

// ---------------------------------------------------------------------------
// Kernel 1: dual GEMM via bf16 MFMA (unchanged from R4).
// self = x@W1^T (fp32 -> out), neigh = x@W2^T (bf16 -> ws).
// ---------------------------------------------------------------------------
__global__ __launch_bounds__(256, 2) void gemm_kernel(
    const float* __restrict__ x, const float* __restrict__ W1,
    const float* __restrict__ W2, float* __restrict__ self_out,
    unsigned short* __restrict__ neigh) {
  __shared__ unsigned short xs[128 * 136];  // 34 KB

  const int tid = threadIdx.x;
  const int lane = tid & 63;
  const int w = tid >> 6;
  const int nb = blockIdx.x * 128;
  const int quad = lane >> 4;
  const int l15 = lane & 15;

  bf16x8 bfrag[4][4];
#pragma unroll
  for (int nt = 0; nt < 4; ++nt) {
    const int j = w * 64 + nt * 16 + l15;
    const float* Wrow =
        (j < 128) ? (W1 + (size_t)j * DIM) : (W2 + (size_t)(j - 128) * DIM);
#pragma unroll
    for (int ks = 0; ks < 4; ++ks) {
      const float* p = Wrow + ks * 32 + quad * 8;
      const float4 lo = *(const float4*)(p);
      const float4 hi = *(const float4*)(p + 4);
      bf16x8 t;
      t[0] = (short)f2bf(lo.x); t[1] = (short)f2bf(lo.y);
      t[2] = (short)f2bf(lo.z); t[3] = (short)f2bf(lo.w);
      t[4] = (short)f2bf(hi.x); t[5] = (short)f2bf(hi.y);
      t[6] = (short)f2bf(hi.z); t[7] = (short)f2bf(hi.w);
      bfrag[nt][ks] = t;
    }
  }

#pragma unroll
  for (int it = 0; it < 16; ++it) {
    const int v = tid + it * 256;
    const int m = v >> 5, q = v & 31;
    float4 val = make_float4(0.f, 0.f, 0.f, 0.f);
    if (nb + m < N_NODES)
      val = *(const float4*)(x + (size_t)(nb + m) * DIM + 4 * q);
    unsigned short* d = &xs[m * 136 + 4 * q];
    d[0] = f2bf(val.x); d[1] = f2bf(val.y);
    d[2] = f2bf(val.z); d[3] = f2bf(val.w);
  }
  __syncthreads();

  f32x4 acc[8][4];
#pragma unroll
  for (int mt = 0; mt < 8; ++mt)
#pragma unroll
    for (int nt = 0; nt < 4; ++nt) acc[mt][nt] = (f32x4){0.f, 0.f, 0.f, 0.f};

#pragma unroll
  for (int ks = 0; ks < 4; ++ks) {
#pragma unroll
    for (int mt = 0; mt < 8; ++mt) {
      const bf16x8 afrag =
          *(const bf16x8*)&xs[(mt * 16 + l15) * 136 + ks * 32 + quad * 8];
#pragma unroll
      for (int nt = 0; nt < 4; ++nt)
        acc[mt][nt] = __builtin_amdgcn_mfma_f32_16x16x32_bf16(
            afrag, bfrag[nt][ks], acc[mt][nt], 0, 0, 0);
    }
  }

#pragma unroll
  for (int mt = 0; mt < 8; ++mt) {
#pragma unroll
    for (int nt = 0; nt < 4; ++nt) {
      const int j = w * 64 + nt * 16 + l15;
#pragma unroll
      for (int r = 0; r < 4; ++r) {
        const int node = nb + mt * 16 + quad * 4 + r;
        if (node < N_NODES) {
          if (w < 2)
            self_out[(size_t)node * DIM + j] = acc[mt][nt][r];
          else
            neigh[(size_t)node * DIM + (j - 128)] = f2bf(acc[mt][nt][r]);
        }
      }
    }
  }
}

// ---------------------------------------------------------------------------
// Kernel 2: LDS-staged binning. Entries packed (r&511)<<17 | c into LDS bins,
// flushed wave-coalesced to block-private binned[bin][blk][FCAP]. No global
// atomics (R3 lesson), no scattered global stores (R2/R4 lesson).
// ---------------------------------------------------------------------------
__global__ __launch_bounds__(256, 2) void fill_kernel(
    const int* __restrict__ rows, const int* __restrict__ cols,
    int* __restrict__ counts, unsigned* __restrict__ binned,
    const unsigned short* __restrict__ neigh, float* __restrict__ out,
    int n_edges) {
  __shared__ unsigned buf[NB * FCAP];  // 62.7 KB
  __shared__ int lcnt[NB];
  const int tid = threadIdx.x;
  for (int i = tid; i < NB; i += 256) lcnt[i] = 0;
  __syncthreads();

  const int chunk = (n_edges + NFILL - 1) / NFILL;
  const int e0 = blockIdx.x * chunk;
  const int e1 = min(e0 + chunk, n_edges);
  for (int e = e0 + tid; e < e1; e += 256) {
    const int r = rows[e];
    const int c = cols[e];
    const int b = r >> 9;
    const unsigned payload = ((unsigned)(r & 511) << 17) | (unsigned)c;
    const int slot = atomicAdd(&lcnt[b], 1);
    if (slot < FCAP) {
      buf[b * FCAP + slot] = payload;
    } else {  // ~never: add contribution directly (pre-ReLU)
      for (int d = 0; d < DIM; ++d)
        atomicAdd(&out[(size_t)r * DIM + d], bf2f(neigh[(size_t)c * DIM + d]));
    }
  }
  __syncthreads();

  // wave-coalesced flush; counts[bin][blk] always written (incl. 0)
  const int w = tid >> 6, l = tid & 63;
  for (int b = w; b < NB; b += 4) {
    const int cnt = min(lcnt[b], FCAP);
    unsigned* dst = binned + ((size_t)b * NFILL + blockIdx.x) * FCAP;
    for (int i = l; i < cnt; i += 64) dst[i] = buf[b * FCAP + i];
    if (l == 0) counts[b * NFILL + blockIdx.x] = cnt;
  }
}

// ---------------------------------------------------------------------------
// Kernel 3: per-bin counting sort -> exact global CSR (row_ptr, deg, cols).
// One block per bin (512 nodes). All global writes coalesced/bin-private.
// ---------------------------------------------------------------------------
__global__ __launch_bounds__(256) void sort_kernel(
    const int* __restrict__ counts, const unsigned* __restrict__ binned,
    int* __restrict__ csr_cols, int* __restrict__ row_ptr,
    int* __restrict__ degs, const unsigned short* __restrict__ neigh,
    float* __restrict__ out) {
  __shared__ int entbuf[ENTCAP];  // 34.8 KB
  __shared__ int segc[NFILL];
  __shared__ int sega[NFILL];
  __shared__ int hist[512];
  __shared__ int sa[512], sb[512];
  __shared__ int cur[512];

  const int tid = threadIdx.x;
  const int bin = blockIdx.x;

  // per-fill-block counts + inclusive scan (256 threads, Hillis-Steele)
  segc[tid] = counts[bin * NFILL + tid];
  __syncthreads();
  sega[tid] = segc[tid];
  __syncthreads();
  for (int off = 1; off < 256; off <<= 1) {
    const int v = sega[tid] + ((tid >= off) ? sega[tid - off] : 0);
    __syncthreads();
    sega[tid] = v;
    __syncthreads();
  }

  // compact segments into entbuf (wave per fill-block, lanes coalesced)
  const int w = tid >> 6, l = tid & 63;
  for (int blk = w; blk < NFILL; blk += 4) {
    const int cnt = segc[blk];
    const int base = sega[blk] - cnt;  // exclusive prefix
    const unsigned* src = binned + ((size_t)bin * NFILL + blk) * FCAP;
    for (int i = l; i < cnt; i += 64) {
      const int pos = base + i;
      if (pos < ENTCAP) {
        entbuf[pos] = (int)src[i];
      } else {  // ~never overflow: direct add
        const unsigned p = src[i];
        const int r = (bin << 9) | (int)(p >> 17);
        const int c = (int)(p & 0x1FFFFu);
        for (int d = 0; d < DIM; ++d)
          atomicAdd(&out[(size_t)r * DIM + d],
                    bf2f(neigh[(size_t)c * DIM + d]));
      }
    }
  }
  for (int i = tid; i < 512; i += 256) hist[i] = 0;
  __syncthreads();

  const int total = min(sega[NFILL - 1], ENTCAP);
  for (int i = tid; i < total; i += 256)
    atomicAdd(&hist[((unsigned)entbuf[i]) >> 17], 1);
  __syncthreads();

  // 512-wide scan of hist
  for (int i = tid; i < 512; i += 256) sa[i] = hist[i];
  __syncthreads();
  for (int off = 1; off < 512; off <<= 1) {
    for (int i = tid; i < 512; i += 256)
      sb[i] = sa[i] + ((i >= off) ? sa[i - off] : 0);
    __syncthreads();
    for (int i = tid; i < 512; i += 256) sa[i] = sb[i];
    __syncthreads();
  }

  const int gbase = bin * ENTCAP;
  for (int i = tid; i < 512; i += 256) {
    const int start = sa[i] - hist[i];  // exclusive
    cur[i] = start;
    const int node = (bin << 9) | i;
    if (node < N_NODES) {
      row_ptr[node] = gbase + start;
      degs[node] = hist[i];
    }
  }
  __syncthreads();

  // scatter into bin-private CSR region (L2-hot 34 KB window)
  for (int i = tid; i < total; i += 256) {
    const unsigned p = (unsigned)entbuf[i];
    const int rl = (int)(p >> 17);
    const int c = (int)(p & 0x1FFFFu);
    const int pos = atomicAdd(&cur[rl], 1);  // pos < total <= ENTCAP
    csr_cols[gbase + pos] = c;
  }
}

// ---------------------------------------------------------------------------
// Kernel 4: wave-per-node gather-reduce (bf16) + add-self + ReLU. Exact degs.
// ---------------------------------------------------------------------------
__global__ __launch_bounds__(256) void agg_kernel(
    const int* __restrict__ row_ptr, const int* __restrict__ degs,
    const int* __restrict__ csr_cols, const unsigned short* __restrict__ neigh,
    float* __restrict__ out) {
  const int node = blockIdx.x * 4 + (threadIdx.x >> 6);
  if (node >= N_NODES) return;
  const int l = threadIdx.x & 63;
  const int deg = degs[node];
  const int* cl = csr_cols + row_ptr[node];
  const unsigned* ng = (const unsigned*)neigh;

  float ax = 0.f, ay = 0.f;
  int d = 0;
  for (; d + 4 <= deg; d += 4) {
    const int c0 = cl[d + 0];
    const int c1 = cl[d + 1];
    const int c2 = cl[d + 2];
    const int c3 = cl[d + 3];
    const unsigned u0 = ng[(size_t)c0 * 64 + l];
    const unsigned u1 = ng[(size_t)c1 * 64 + l];
    const unsigned u2 = ng[(size_t)c2 * 64 + l];
    const unsigned u3 = ng[(size_t)c3 * 64 + l];
    ax += (__builtin_bit_cast(float, u0 << 16) +
           __builtin_bit_cast(float, u1 << 16)) +
          (__builtin_bit_cast(float, u2 << 16) +
           __builtin_bit_cast(float, u3 << 16));
    ay += (__builtin_bit_cast(float, u0 & 0xffff0000u) +
           __builtin_bit_cast(float, u1 & 0xffff0000u)) +
          (__builtin_bit_cast(float, u2 & 0xffff0000u) +
           __builtin_bit_cast(float, u3 & 0xffff0000u));
  }
  for (; d < deg; ++d) {
    const unsigned u = ng[(size_t)cl[d] * 64 + l];
    ax += __builtin_bit_cast(float, u << 16);
    ay += __builtin_bit_cast(float, u & 0xffff0000u);
  }

  float2 s = *(const float2*)(out + (size_t)node * DIM + 2 * l);
  s.x = fmaxf(s.x + ax, 0.f);
  s.y = fmaxf(s.y + ay, 0.f);
  *(float2*)(out + (size_t)node * DIM + 2 * l) = s;
}

extern "C" void kernel_launch(void* const* d_in, const int* in_sizes, int n_in,
                              void* d_out, int out_size, void* d_ws,
                              size_t ws_size, hipStream_t stream) {
  const float* x = (const float*)d_in[0];
  const int* edge_index = (const int*)d_in[1];  // (2,E): [0]=row(dst), [1]=col(src)
  const float* W1 = (const float*)d_in[2];
  const float* W2 = (const float*)d_in[3];
  float* out = (float*)d_out;

  const int n_edges = in_sizes[1] / 2;
  const int* rows = edge_index;
  const int* cols = edge_index + n_edges;

  // ws layout (~49.5 MB):
  // neigh bf16 25.6 MB | binned 16.06 MB | counts 0.2 MB | csr 6.82 MB |
  // row_ptr 0.4 MB | degs 0.4 MB
  char* p = (char*)d_ws;
  unsigned short* neigh = (unsigned short*)p;
  p += (size_t)N_NODES * DIM * 2;
  unsigned* binned = (unsigned*)p;
  p += (size_t)NB * NFILL * FCAP * 4;
  int* counts = (int*)p;
  p += (size_t)NB * NFILL * 4;
  int* csr_cols = (int*)p;
  p += (size_t)NB * ENTCAP * 4;
  int* row_ptr = (int*)p;
  p += (size_t)N_NODES * 4;
  int* degs = (int*)p;

  const int n_tiles = (N_NODES + 127) / 128;  // 782
  gemm_kernel<<<n_tiles, 256, 0, stream>>>(x, W1, W2, out, neigh);
  fill_kernel<<<NFILL, 256, 0, stream>>>(rows, cols, counts, binned, neigh,
                                         out, n_edges);
  sort_kernel<<<NB, 256, 0, stream>>>(counts, binned, csr_cols, row_ptr, degs,
                                      neigh, out);
  agg_kernel<<<(N_NODES + 3) / 4, 256, 0, stream>>>(row_ptr, degs, csr_cols,
                                                    neigh, out);
}

// Round 6
// 285.083 us; speedup vs baseline: 2.1803x; 1.0286x over previous
//
#include <hip/hip_runtime.h>

#define N_NODES 100000
#define DIM 128
#define NB 196       // node bins of 512: bin = r >> 9
#define NFILL 256    // fill blocks; chunk = E/256 = 6250
#define FCAP 80      // per-(block,bin) slots; mean 32, P(Binom>80) ~ 1e-17
#define ENTCAP 8704  // per-bin CSR capacity; mean 8163, ~6 sigma
#define SPCAP 4096   // global spill capacity (never used in practice)

typedef __attribute__((ext_vector_type(8))) short bf16x8;
typedef __attribute__((ext_vector_type(4))) float f32x4;

__device__ __forceinline__ unsigned short f2bf(float f) {
  unsigned u = __builtin_bit_cast(unsigned, f);
  u += 0x7fff + ((u >> 16) & 1);  // RNE
  return (unsigned short)(u >> 16);
}
__device__ __forceinline__ float bfhi(unsigned u) {  // high bf16 of dword
  return __builtin_bit_cast(float, u & 0xffff0000u);
}
__device__ __forceinline__ float bflo(unsigned u) {  // low bf16 of dword
  return __builtin_bit_cast(float, u << 16);
}

// ---------------------------------------------------------------------------
// Kernel 1: dual GEMM via bf16 MFMA.  selfb = x@W1^T (bf16 -> ws),
// neigh = x@W2^T (bf16 -> ws).  Tile 128 nodes x 256 j, K=128 one stage.
// Staging packs bf16x4 -> single 8B LDS store (was 4x ds_write_u16).
// ---------------------------------------------------------------------------
__global__ __launch_bounds__(256, 2) void gemm_kernel(
    const float* __restrict__ x, const float* __restrict__ W1,
    const float* __restrict__ W2, unsigned short* __restrict__ selfb,
    unsigned short* __restrict__ neigh) {
  __shared__ unsigned short xs[128 * 136];  // 34 KB

  const int tid = threadIdx.x;
  const int lane = tid & 63;
  const int w = tid >> 6;
  const int nb = blockIdx.x * 128;
  const int quad = lane >> 4;
  const int l15 = lane & 15;

  // B fragments: B[k][n] = W[j=n][k]; j = 64w + 16nt + l15, k = 32ks+8quad+t
  bf16x8 bfrag[4][4];
#pragma unroll
  for (int nt = 0; nt < 4; ++nt) {
    const int j = w * 64 + nt * 16 + l15;
    const float* Wrow =
        (j < 128) ? (W1 + (size_t)j * DIM) : (W2 + (size_t)(j - 128) * DIM);
#pragma unroll
    for (int ks = 0; ks < 4; ++ks) {
      const float* p = Wrow + ks * 32 + quad * 8;
      const float4 lo = *(const float4*)(p);
      const float4 hi = *(const float4*)(p + 4);
      bf16x8 t;
      t[0] = (short)f2bf(lo.x); t[1] = (short)f2bf(lo.y);
      t[2] = (short)f2bf(lo.z); t[3] = (short)f2bf(lo.w);
      t[4] = (short)f2bf(hi.x); t[5] = (short)f2bf(hi.y);
      t[6] = (short)f2bf(hi.z); t[7] = (short)f2bf(hi.w);
      bfrag[nt][ks] = t;
    }
  }

  // stage A: 128 rows x 128 k, fp32 -> bf16 packed 8B stores, row stride 136
#pragma unroll
  for (int it = 0; it < 16; ++it) {
    const int v = tid + it * 256;
    const int m = v >> 5, q = v & 31;
    float4 val = make_float4(0.f, 0.f, 0.f, 0.f);
    if (nb + m < N_NODES)
      val = *(const float4*)(x + (size_t)(nb + m) * DIM + 4 * q);
    const unsigned lo = (unsigned)f2bf(val.x) | ((unsigned)f2bf(val.y) << 16);
    const unsigned hi = (unsigned)f2bf(val.z) | ((unsigned)f2bf(val.w) << 16);
    *(uint2*)&xs[m * 136 + 4 * q] = make_uint2(lo, hi);  // 8B aligned
  }
  __syncthreads();

  f32x4 acc[8][4];
#pragma unroll
  for (int mt = 0; mt < 8; ++mt)
#pragma unroll
    for (int nt = 0; nt < 4; ++nt) acc[mt][nt] = (f32x4){0.f, 0.f, 0.f, 0.f};

#pragma unroll
  for (int ks = 0; ks < 4; ++ks) {
#pragma unroll
    for (int mt = 0; mt < 8; ++mt) {
      const bf16x8 afrag =
          *(const bf16x8*)&xs[(mt * 16 + l15) * 136 + ks * 32 + quad * 8];
#pragma unroll
      for (int nt = 0; nt < 4; ++nt)
        acc[mt][nt] = __builtin_amdgcn_mfma_f32_16x16x32_bf16(
            afrag, bfrag[nt][ks], acc[mt][nt], 0, 0, 0);
    }
  }

  // epilogue: D[row = 16mt + 4quad + r][col = 64w + 16nt + l15], bf16 stores
  unsigned short* base = (w < 2) ? selfb : neigh;
#pragma unroll
  for (int mt = 0; mt < 8; ++mt) {
#pragma unroll
    for (int nt = 0; nt < 4; ++nt) {
      const int j = (w * 64 + nt * 16 + l15) & 127;
#pragma unroll
      for (int r = 0; r < 4; ++r) {
        const int node = nb + mt * 16 + quad * 4 + r;
        if (node < N_NODES)
          base[(size_t)node * DIM + j] = f2bf(acc[mt][nt][r]);
      }
    }
  }
}

// ---------------------------------------------------------------------------
// Kernel 2: LDS-staged binning, wave-coalesced flush (R5 win, kept).
// Overflow -> global spill list (handled in agg), no deps on gemm output.
// ---------------------------------------------------------------------------
__global__ __launch_bounds__(256, 2) void fill_kernel(
    const int* __restrict__ rows, const int* __restrict__ cols,
    int* __restrict__ counts, unsigned* __restrict__ binned,
    int* __restrict__ spill_cnt, int2* __restrict__ spill, int n_edges) {
  __shared__ unsigned buf[NB * FCAP];  // 62.7 KB
  __shared__ int lcnt[NB];
  const int tid = threadIdx.x;
  for (int i = tid; i < NB; i += 256) lcnt[i] = 0;
  __syncthreads();

  const int chunk = (n_edges + NFILL - 1) / NFILL;
  const int e0 = blockIdx.x * chunk;
  const int e1 = min(e0 + chunk, n_edges);
  for (int e = e0 + tid; e < e1; e += 256) {
    const int r = rows[e];
    const int c = cols[e];
    const int b = r >> 9;
    const unsigned payload = ((unsigned)(r & 511) << 17) | (unsigned)c;
    const int slot = atomicAdd(&lcnt[b], 1);
    if (slot < FCAP) {
      buf[b * FCAP + slot] = payload;
    } else {  // ~never
      const int sp = atomicAdd(spill_cnt, 1);
      if (sp < SPCAP) spill[sp] = make_int2(r, c);
    }
  }
  __syncthreads();

  const int w = tid >> 6, l = tid & 63;
  for (int b = w; b < NB; b += 4) {
    const int cnt = min(lcnt[b], FCAP);
    unsigned* dst = binned + ((size_t)b * NFILL + blockIdx.x) * FCAP;
    for (int i = l; i < cnt; i += 64) dst[i] = buf[b * FCAP + i];
    if (l == 0) counts[b * NFILL + blockIdx.x] = cnt;
  }
}

// ---------------------------------------------------------------------------
// Kernel 3: per-bin counting sort -> exact CSR (row_ptr, deg, cols).
// ---------------------------------------------------------------------------
__global__ __launch_bounds__(256) void sort_kernel(
    const int* __restrict__ counts, const unsigned* __restrict__ binned,
    int* __restrict__ csr_cols, int* __restrict__ row_ptr,
    int* __restrict__ degs, int* __restrict__ spill_cnt,
    int2* __restrict__ spill) {
  __shared__ int entbuf[ENTCAP];  // 34.8 KB
  __shared__ int segc[NFILL];
  __shared__ int sega[NFILL];
  __shared__ int hist[512];
  __shared__ int sa[512], sb[512];
  __shared__ int cur[512];

  const int tid = threadIdx.x;
  const int bin = blockIdx.x;

  segc[tid] = counts[bin * NFILL + tid];
  __syncthreads();
  sega[tid] = segc[tid];
  __syncthreads();
  for (int off = 1; off < 256; off <<= 1) {
    const int v = sega[tid] + ((tid >= off) ? sega[tid - off] : 0);
    __syncthreads();
    sega[tid] = v;
    __syncthreads();
  }

  const int w = tid >> 6, l = tid & 63;
  for (int blk = w; blk < NFILL; blk += 4) {
    const int cnt = segc[blk];
    const int base = sega[blk] - cnt;
    const unsigned* src = binned + ((size_t)bin * NFILL + blk) * FCAP;
    for (int i = l; i < cnt; i += 64) {
      const int pos = base + i;
      const unsigned p = src[i];
      if (pos < ENTCAP) {
        entbuf[pos] = (int)p;
      } else {  // ~never
        const int sp = atomicAdd(spill_cnt, 1);
        if (sp < SPCAP)
          spill[sp] =
              make_int2((bin << 9) | (int)(p >> 17), (int)(p & 0x1FFFFu));
      }
    }
  }
  for (int i = tid; i < 512; i += 256) hist[i] = 0;
  __syncthreads();

  const int total = min(sega[NFILL - 1], ENTCAP);
  for (int i = tid; i < total; i += 256)
    atomicAdd(&hist[((unsigned)entbuf[i]) >> 17], 1);
  __syncthreads();

  for (int i = tid; i < 512; i += 256) sa[i] = hist[i];
  __syncthreads();
  for (int off = 1; off < 512; off <<= 1) {
    for (int i = tid; i < 512; i += 256)
      sb[i] = sa[i] + ((i >= off) ? sa[i - off] : 0);
    __syncthreads();
    for (int i = tid; i < 512; i += 256) sa[i] = sb[i];
    __syncthreads();
  }

  const int gbase = bin * ENTCAP;
  for (int i = tid; i < 512; i += 256) {
    const int start = sa[i] - hist[i];
    cur[i] = start;
    const int node = (bin << 9) | i;
    if (node < N_NODES) {
      row_ptr[node] = gbase + start;
      degs[node] = hist[i];
    }
  }
  __syncthreads();

  for (int i = tid; i < total; i += 256) {
    const unsigned p = (unsigned)entbuf[i];
    const int rl = (int)(p >> 17);
    const int c = (int)(p & 0x1FFFFu);
    const int pos = atomicAdd(&cur[rl], 1);
    csr_cols[gbase + pos] = c;
  }
}

// ---------------------------------------------------------------------------
// Kernel 4: wave-per-node gather (bf16, 8-deep masked ILP) + self + ReLU.
// Sole writer of out. Spill list merged here (~never non-empty).
// ---------------------------------------------------------------------------
__global__ __launch_bounds__(256) void agg_kernel(
    const int* __restrict__ row_ptr, const int* __restrict__ degs,
    const int* __restrict__ csr_cols, const unsigned short* __restrict__ neigh,
    const unsigned short* __restrict__ selfb, const int* __restrict__ spill_cnt,
    const int2* __restrict__ spill, float* __restrict__ out) {
  const int node = blockIdx.x * 4 + (threadIdx.x >> 6);
  if (node >= N_NODES) return;
  const int l = threadIdx.x & 63;
  const int deg = degs[node];
  const int* cl = csr_cols + row_ptr[node];
  const unsigned* ng = (const unsigned*)neigh;

  float ax = 0.f, ay = 0.f;
  const int rounds = (deg + 7) >> 3;
  for (int rd = 0; rd < rounds; ++rd) {
    const int base = rd << 3;
    int idx[8];
    unsigned uv[8];
#pragma unroll
    for (int k = 0; k < 8; ++k) {
      const int dd = base + k;
      idx[k] = cl[dd < deg ? dd : deg - 1];
    }
#pragma unroll
    for (int k = 0; k < 8; ++k) uv[k] = ng[(size_t)idx[k] * 64 + l];
#pragma unroll
    for (int k = 0; k < 8; ++k) {
      if (base + k < deg) {
        ax += bflo(uv[k]);
        ay += bfhi(uv[k]);
      }
    }
  }

  // spill merge (~never taken; one uniform load when empty)
  const int sc = min(*spill_cnt, SPCAP);
  for (int i = 0; i < sc; ++i) {
    const int2 e = spill[i];
    if (e.x == node) {
      const unsigned u = ng[(size_t)e.y * 64 + l];
      ax += bflo(u);
      ay += bfhi(u);
    }
  }

  const unsigned s = ((const unsigned*)selfb)[(size_t)node * 64 + l];
  float2 o;
  o.x = fmaxf(bflo(s) + ax, 0.f);
  o.y = fmaxf(bfhi(s) + ay, 0.f);
  *(float2*)(out + (size_t)node * DIM + 2 * l) = o;
}

extern "C" void kernel_launch(void* const* d_in, const int* in_sizes, int n_in,
                              void* d_out, int out_size, void* d_ws,
                              size_t ws_size, hipStream_t stream) {
  const float* x = (const float*)d_in[0];
  const int* edge_index = (const int*)d_in[1];  // (2,E): [0]=row(dst), [1]=col(src)
  const float* W1 = (const float*)d_in[2];
  const float* W2 = (const float*)d_in[3];
  float* out = (float*)d_out;

  const int n_edges = in_sizes[1] / 2;
  const int* rows = edge_index;
  const int* cols = edge_index + n_edges;

  // ws layout (~75.6 MB): selfb 25.6 | neigh 25.6 | binned 16.06 |
  // counts 0.2 | csr 6.82 | row_ptr 0.4 | degs 0.4 | spill ~0.03
  char* p = (char*)d_ws;
  unsigned short* selfb = (unsigned short*)p;
  p += (size_t)N_NODES * DIM * 2;
  unsigned short* neigh = (unsigned short*)p;
  p += (size_t)N_NODES * DIM * 2;
  unsigned* binned = (unsigned*)p;
  p += (size_t)NB * NFILL * FCAP * 4;
  int* counts = (int*)p;
  p += (size_t)NB * NFILL * 4;
  int* csr_cols = (int*)p;
  p += (size_t)NB * ENTCAP * 4;
  int* row_ptr = (int*)p;
  p += (size_t)N_NODES * 4;
  int* degs = (int*)p;
  p += (size_t)N_NODES * 4;
  int* spill_cnt = (int*)p;
  p += 16;  // keep int2 alignment
  int2* spill = (int2*)p;

  hipMemsetAsync(spill_cnt, 0, 4, stream);

  const int n_tiles = (N_NODES + 127) / 128;  // 782
  gemm_kernel<<<n_tiles, 256, 0, stream>>>(x, W1, W2, selfb, neigh);
  fill_kernel<<<NFILL, 256, 0, stream>>>(rows, cols, counts, binned, spill_cnt,
                                         spill, n_edges);
  sort_kernel<<<NB, 256, 0, stream>>>(counts, binned, csr_cols, row_ptr, degs,
                                      spill_cnt, spill);
  agg_kernel<<<(N_NODES + 3) / 4, 256, 0, stream>>>(
      row_ptr, degs, csr_cols, neigh, selfb, spill_cnt, spill, out);
}

// Round 7
// 274.901 us; speedup vs baseline: 2.2611x; 1.0370x over previous
//
#include <hip/hip_runtime.h>

#define N_NODES 100000
#define DIM 128
#define NB 196       // node bins of 512: bin = r >> 9
#define NFILL 256    // fill blocks; chunk = E/256 = 6250
#define FCAP 80      // per-(block,bin) slots; mean 32, P(Binom>80) ~ 1e-17
#define ENTCAP 8704  // per-bin CSR capacity; mean 8163, +6 sigma
#define SPCAP 4096   // global spill capacity (never used in practice)

typedef __attribute__((ext_vector_type(8))) short bf16x8;
typedef __attribute__((ext_vector_type(4))) float f32x4;

__device__ __forceinline__ unsigned short f2bf(float f) {
  unsigned u = __builtin_bit_cast(unsigned, f);
  u += 0x7fff + ((u >> 16) & 1);  // RNE
  return (unsigned short)(u >> 16);
}
__device__ __forceinline__ float bfhi(unsigned u) {
  return __builtin_bit_cast(float, u & 0xffff0000u);
}
__device__ __forceinline__ float bflo(unsigned u) {
  return __builtin_bit_cast(float, u << 16);
}

// ---------------------------------------------------------------------------
// Kernel 0: convert W1||W2 (fp32, 256x128) to Wb (bf16) once.  Also zeroes
// spill_cnt (first dispatch in the stream -> ordered before fill/sort/agg).
// ---------------------------------------------------------------------------
__global__ __launch_bounds__(256) void wconv_kernel(
    const float* __restrict__ W1, const float* __restrict__ W2,
    unsigned short* __restrict__ Wb, int* __restrict__ spill_cnt) {
  if (blockIdx.x == 0 && threadIdx.x == 0) *spill_cnt = 0;
  const int v = blockIdx.x * 256 + threadIdx.x;  // 8192 float4s
  const int j = v >> 5, q = v & 31;
  const float* Wrow =
      (j < 128) ? (W1 + (size_t)j * DIM) : (W2 + (size_t)(j - 128) * DIM);
  const float4 val = *(const float4*)(Wrow + 4 * q);
  unsigned short* d = Wb + (size_t)j * DIM + 4 * q;
  const unsigned lo = (unsigned)f2bf(val.x) | ((unsigned)f2bf(val.y) << 16);
  const unsigned hi = (unsigned)f2bf(val.z) | ((unsigned)f2bf(val.w) << 16);
  *(uint2*)d = make_uint2(lo, hi);
}

// ---------------------------------------------------------------------------
// Kernel 1: dual GEMM via bf16 MFMA.  selfb = x@W1^T, neigh = x@W2^T (both
// bf16 -> ws).  B frags load straight from pre-converted Wb (16B, L2-hot) —
// no per-block W conversion.  Epilogue stages the bf16 tile in LDS (reuse
// xs) and stores fully-coalesced dwordx4 — no scalar 2B global stores.
// ---------------------------------------------------------------------------
__global__ __launch_bounds__(256, 2) void gemm_kernel(
    const float* __restrict__ x, const unsigned short* __restrict__ Wb,
    unsigned short* __restrict__ selfb, unsigned short* __restrict__ neigh) {
  __shared__ unsigned short xs[128 * 136];  // 34 KB

  const int tid = threadIdx.x;
  const int lane = tid & 63;
  const int w = tid >> 6;
  const int nb = blockIdx.x * 128;
  const int quad = lane >> 4;
  const int l15 = lane & 15;

  // B fragments straight from Wb: j = 64w + 16nt + l15, k = 32ks + 8quad + t
  bf16x8 bfrag[4][4];
#pragma unroll
  for (int nt = 0; nt < 4; ++nt) {
    const int j = w * 64 + nt * 16 + l15;
#pragma unroll
    for (int ks = 0; ks < 4; ++ks)
      bfrag[nt][ks] =
          *(const bf16x8*)(Wb + (size_t)j * DIM + ks * 32 + quad * 8);
  }

  // stage A: 128 rows x 128 k, fp32 -> bf16 packed 8B stores, row stride 136
#pragma unroll
  for (int it = 0; it < 16; ++it) {
    const int v = tid + it * 256;
    const int m = v >> 5, q = v & 31;
    float4 val = make_float4(0.f, 0.f, 0.f, 0.f);
    if (nb + m < N_NODES)
      val = *(const float4*)(x + (size_t)(nb + m) * DIM + 4 * q);
    const unsigned lo = (unsigned)f2bf(val.x) | ((unsigned)f2bf(val.y) << 16);
    const unsigned hi = (unsigned)f2bf(val.z) | ((unsigned)f2bf(val.w) << 16);
    *(uint2*)&xs[m * 136 + 4 * q] = make_uint2(lo, hi);
  }
  __syncthreads();

  f32x4 acc[8][4];
#pragma unroll
  for (int mt = 0; mt < 8; ++mt)
#pragma unroll
    for (int nt = 0; nt < 4; ++nt) acc[mt][nt] = (f32x4){0.f, 0.f, 0.f, 0.f};

#pragma unroll
  for (int ks = 0; ks < 4; ++ks) {
#pragma unroll
    for (int mt = 0; mt < 8; ++mt) {
      const bf16x8 afrag =
          *(const bf16x8*)&xs[(mt * 16 + l15) * 136 + ks * 32 + quad * 8];
#pragma unroll
      for (int nt = 0; nt < 4; ++nt)
        acc[mt][nt] = __builtin_amdgcn_mfma_f32_16x16x32_bf16(
            afrag, bfrag[nt][ks], acc[mt][nt], 0, 0, 0);
    }
  }

  // epilogue: two half-tiles (h=0: selfb from waves 0-1; h=1: neigh from
  // waves 2-3) staged in xs, stored coalesced as dwordx4.
  // D[row = 16mt + 4quad + r][col within half = (w&1)*64 + 16nt + l15]
#pragma unroll
  for (int h = 0; h < 2; ++h) {
    __syncthreads();  // xs free (prev reads/copies done)
    if ((w >> 1) == h) {
#pragma unroll
      for (int mt = 0; mt < 8; ++mt)
#pragma unroll
        for (int nt = 0; nt < 4; ++nt) {
          const int col = (w & 1) * 64 + nt * 16 + l15;
#pragma unroll
          for (int r = 0; r < 4; ++r)
            xs[(mt * 16 + quad * 4 + r) * 136 + col] = f2bf(acc[mt][nt][r]);
        }
    }
    __syncthreads();
    unsigned short* dst = h ? neigh : selfb;
#pragma unroll
    for (int it = 0; it < 8; ++it) {
      const int v = it * 256 + tid;
      const int row = v >> 4, q = v & 15;  // 16 x 16B chunks per 256B row
      if (nb + row < N_NODES)
        *(uint4*)(dst + (size_t)(nb + row) * DIM + 8 * q) =
            *(const uint4*)&xs[row * 136 + 8 * q];
    }
  }
}

// ---------------------------------------------------------------------------
// Kernel 2: LDS-staged binning, wave-coalesced flush (R5 win, kept).
// ---------------------------------------------------------------------------
__global__ __launch_bounds__(256, 2) void fill_kernel(
    const int* __restrict__ rows, const int* __restrict__ cols,
    int* __restrict__ counts, unsigned* __restrict__ binned,
    int* __restrict__ spill_cnt, int2* __restrict__ spill, int n_edges) {
  __shared__ unsigned buf[NB * FCAP];  // 62.7 KB
  __shared__ int lcnt[NB];
  const int tid = threadIdx.x;
  for (int i = tid; i < NB; i += 256) lcnt[i] = 0;
  __syncthreads();

  const int chunk = (n_edges + NFILL - 1) / NFILL;
  const int e0 = blockIdx.x * chunk;
  const int e1 = min(e0 + chunk, n_edges);
  for (int e = e0 + tid; e < e1; e += 256) {
    const int r = rows[e];
    const int c = cols[e];
    const int b = r >> 9;
    const unsigned payload = ((unsigned)(r & 511) << 17) | (unsigned)c;
    const int slot = atomicAdd(&lcnt[b], 1);
    if (slot < FCAP) {
      buf[b * FCAP + slot] = payload;
    } else {  // ~never
      const int sp = atomicAdd(spill_cnt, 1);
      if (sp < SPCAP) spill[sp] = make_int2(r, c);
    }
  }
  __syncthreads();

  const int w = tid >> 6, l = tid & 63;
  for (int b = w; b < NB; b += 4) {
    const int cnt = min(lcnt[b], FCAP);
    unsigned* dst = binned + ((size_t)b * NFILL + blockIdx.x) * FCAP;
    for (int i = l; i < cnt; i += 64) dst[i] = buf[b * FCAP + i];
    if (l == 0) counts[b * NFILL + blockIdx.x] = cnt;
  }
}

// ---------------------------------------------------------------------------
// Kernel 3: per-bin counting sort -> exact CSR (row_ptr, deg, cols).
// ---------------------------------------------------------------------------
__global__ __launch_bounds__(256) void sort_kernel(
    const int* __restrict__ counts, const unsigned* __restrict__ binned,
    int* __restrict__ csr_cols, int* __restrict__ row_ptr,
    int* __restrict__ degs, int* __restrict__ spill_cnt,
    int2* __restrict__ spill) {
  __shared__ int entbuf[ENTCAP];  // 34.8 KB
  __shared__ int segc[NFILL];
  __shared__ int sega[NFILL];
  __shared__ int hist[512];
  __shared__ int sa[512], sb[512];
  __shared__ int cur[512];

  const int tid = threadIdx.x;
  const int bin = blockIdx.x;

  segc[tid] = counts[bin * NFILL + tid];
  __syncthreads();
  sega[tid] = segc[tid];
  __syncthreads();
  for (int off = 1; off < 256; off <<= 1) {
    const int v = sega[tid] + ((tid >= off) ? sega[tid - off] : 0);
    __syncthreads();
    sega[tid] = v;
    __syncthreads();
  }

  const int w = tid >> 6, l = tid & 63;
  for (int blk = w; blk < NFILL; blk += 4) {
    const int cnt = segc[blk];
    const int base = sega[blk] - cnt;
    const unsigned* src = binned + ((size_t)bin * NFILL + blk) * FCAP;
    for (int i = l; i < cnt; i += 64) {
      const int pos = base + i;
      const unsigned p = src[i];
      if (pos < ENTCAP) {
        entbuf[pos] = (int)p;
      } else {  // ~never
        const int sp = atomicAdd(spill_cnt, 1);
        if (sp < SPCAP)
          spill[sp] =
              make_int2((bin << 9) | (int)(p >> 17), (int)(p & 0x1FFFFu));
      }
    }
  }
  for (int i = tid; i < 512; i += 256) hist[i] = 0;
  __syncthreads();

  const int total = min(sega[NFILL - 1], ENTCAP);
  for (int i = tid; i < total; i += 256)
    atomicAdd(&hist[((unsigned)entbuf[i]) >> 17], 1);
  __syncthreads();

  for (int i = tid; i < 512; i += 256) sa[i] = hist[i];
  __syncthreads();
  for (int off = 1; off < 512; off <<= 1) {
    for (int i = tid; i < 512; i += 256)
      sb[i] = sa[i] + ((i >= off) ? sa[i - off] : 0);
    __syncthreads();
    for (int i = tid; i < 512; i += 256) sa[i] = sb[i];
    __syncthreads();
  }

  const int gbase = bin * ENTCAP;
  for (int i = tid; i < 512; i += 256) {
    const int start = sa[i] - hist[i];
    cur[i] = start;
    const int node = (bin << 9) | i;
    if (node < N_NODES) {
      row_ptr[node] = gbase + start;
      degs[node] = hist[i];
    }
  }
  __syncthreads();

  for (int i = tid; i < total; i += 256) {
    const unsigned p = (unsigned)entbuf[i];
    const int rl = (int)(p >> 17);
    const int c = (int)(p & 0x1FFFFu);
    const int pos = atomicAdd(&cur[rl], 1);
    csr_cols[gbase + pos] = c;
  }
}

// ---------------------------------------------------------------------------
// Kernel 4: persistent wave-per-node gather (bf16) + self + ReLU.
// Exact tail (no duplicate-row traffic beyond one cached row), grid sized
// for exactly-full residency (2048 blocks x 1 wave-group = 8 blocks/CU).
// ---------------------------------------------------------------------------
__global__ __launch_bounds__(256) void agg_kernel(
    const int* __restrict__ row_ptr, const int* __restrict__ degs,
    const int* __restrict__ csr_cols, const unsigned short* __restrict__ neigh,
    const unsigned short* __restrict__ selfb, const int* __restrict__ spill_cnt,
    const int2* __restrict__ spill, float* __restrict__ out) {
  const int l = threadIdx.x & 63;
  const int wid = blockIdx.x * 4 + (threadIdx.x >> 6);
  const int stride = gridDim.x * 4;
  const unsigned* ng = (const unsigned*)neigh;
  const int sc = min(*spill_cnt, SPCAP);

  for (int node = wid; node < N_NODES; node += stride) {
    const int deg = degs[node];
    const int* cl = csr_cols + row_ptr[node];
    const unsigned s = ((const unsigned*)selfb)[(size_t)node * 64 + l];

    float ax = 0.f, ay = 0.f;
    int d = 0;
    for (; d + 8 <= deg; d += 8) {
      unsigned uv[8];
#pragma unroll
      for (int k = 0; k < 8; ++k) uv[k] = ng[(size_t)cl[d + k] * 64 + l];
#pragma unroll
      for (int k = 0; k < 8; ++k) {
        ax += bflo(uv[k]);
        ay += bfhi(uv[k]);
      }
    }
    const int rem = deg - d;
    if (rem) {
      unsigned uv[8];
      const int cdup = cl[d];  // dup address stays in-cache (single row)
#pragma unroll
      for (int k = 0; k < 8; ++k) {
        const int ci = (k < rem) ? cl[d + k] : cdup;
        uv[k] = ng[(size_t)ci * 64 + l];
      }
#pragma unroll
      for (int k = 0; k < 8; ++k) {
        if (k < rem) {  // wave-uniform mask
          ax += bflo(uv[k]);
          ay += bfhi(uv[k]);
        }
      }
    }

    for (int i = 0; i < sc; ++i) {  // ~never non-empty
      const int2 e = spill[i];
      if (e.x == node) {
        const unsigned u = ng[(size_t)e.y * 64 + l];
        ax += bflo(u);
        ay += bfhi(u);
      }
    }

    float2 o;
    o.x = fmaxf(bflo(s) + ax, 0.f);
    o.y = fmaxf(bfhi(s) + ay, 0.f);
    *(float2*)(out + (size_t)node * DIM + 2 * l) = o;
  }
}

extern "C" void kernel_launch(void* const* d_in, const int* in_sizes, int n_in,
                              void* d_out, int out_size, void* d_ws,
                              size_t ws_size, hipStream_t stream) {
  const float* x = (const float*)d_in[0];
  const int* edge_index = (const int*)d_in[1];  // (2,E): [0]=row(dst), [1]=col(src)
  const float* W1 = (const float*)d_in[2];
  const float* W2 = (const float*)d_in[3];
  float* out = (float*)d_out;

  const int n_edges = in_sizes[1] / 2;
  const int* rows = edge_index;
  const int* cols = edge_index + n_edges;

  // ws layout (~75.3 MB): selfb 25.6 | neigh 25.6 | binned 16.06 |
  // counts 0.2 | csr 6.82 | row_ptr 0.4 | degs 0.4 | spill_cnt | spill | Wb
  char* p = (char*)d_ws;
  unsigned short* selfb = (unsigned short*)p;
  p += (size_t)N_NODES * DIM * 2;
  unsigned short* neigh = (unsigned short*)p;
  p += (size_t)N_NODES * DIM * 2;
  unsigned* binned = (unsigned*)p;
  p += (size_t)NB * NFILL * FCAP * 4;
  int* counts = (int*)p;
  p += (size_t)NB * NFILL * 4;
  int* csr_cols = (int*)p;
  p += (size_t)NB * ENTCAP * 4;
  int* row_ptr = (int*)p;
  p += (size_t)N_NODES * 4;
  int* degs = (int*)p;
  p += (size_t)N_NODES * 4;
  int* spill_cnt = (int*)p;
  p += 16;  // int2 alignment
  int2* spill = (int2*)p;
  p += (size_t)SPCAP * sizeof(int2);
  unsigned short* Wb = (unsigned short*)p;  // 256*128 bf16 = 64 KB

  wconv_kernel<<<32, 256, 0, stream>>>(W1, W2, Wb, spill_cnt);
  const int n_tiles = (N_NODES + 127) / 128;  // 782
  gemm_kernel<<<n_tiles, 256, 0, stream>>>(x, Wb, selfb, neigh);
  fill_kernel<<<NFILL, 256, 0, stream>>>(rows, cols, counts, binned, spill_cnt,
                                         spill, n_edges);
  sort_kernel<<<NB, 256, 0, stream>>>(counts, binned, csr_cols, row_ptr, degs,
                                      spill_cnt, spill);
  agg_kernel<<<2048, 256, 0, stream>>>(row_ptr, degs, csr_cols, neigh, selfb,
                                       spill_cnt, spill, out);
}